// Round 2
// baseline (626.957 us; speedup 1.0000x reference)
//
#include <hip/hip_runtime.h>
#include <hip/hip_cooperative_groups.h>

namespace cg = cooperative_groups;

#define NB 48
#define NT 5000
#define NF 161
#define NROWS (NB * NT)               // 240000
#define MAGN  ((size_t)NROWS * NF)    // 38640000
#define GRID  1024
#define TPB   256

typedef float vf4 __attribute__((ext_vector_type(4)));

// ---------------- fused cooperative kernel ----------------
// Phase A: per-row weighted power + sqrt (grid-stride over 15000 groups of 16 rows)
// Phase B: per-batch affine-scan EMA (blocks 0..47)
// Phase C: new_mag = mag * rcp(gain+1e-3) (grid-stride, float4)
__global__ __launch_bounds__(TPB, 4) void fused_kernel(const float* __restrict__ mag,
                                                       float* __restrict__ out,
                                                       float* __restrict__ gout) {
    cg::grid_group grid = cg::this_grid();
    __shared__ __align__(16) float sbuf[NT];   // 20000 B; phase A uses first 2576
    __shared__ float sA[TPB];
    __shared__ float sB[TPB];

    const int tid  = threadIdx.x;
    const int wave = tid >> 6;
    const int lane = tid & 63;

    // ---------- Phase A ----------
    for (int g = blockIdx.x; g < NROWS / 16; g += gridDim.x) {
        const size_t blk_base = (size_t)g * (16 * NF);
        const float4* gp4 = (const float4*)(mag + blk_base);
        float4* sp4 = (float4*)sbuf;
#pragma unroll
        for (int j = 0; j < 3; ++j) {
            int i4 = tid + TPB * j;
            if (i4 < (16 * NF) / 4) sp4[i4] = gp4[i4];
        }
        __syncthreads();

#pragma unroll
        for (int i = 0; i < 4; ++i) {
            const int r = wave * 4 + i;
            const float* rp = sbuf + r * NF;
            float sum = 0.f;
#pragma unroll
            for (int k0 = 0; k0 < NF; k0 += 64) {
                int k = k0 + lane;
                if (k < NF) {
                    float v = rp[k];
                    float w = (k == 0 || k == NF - 1) ? 1.f : 2.f;
                    sum += w * v * v;
                }
            }
#pragma unroll
            for (int off = 32; off > 0; off >>= 1)
                sum += __shfl_down(sum, off, 64);
            if (lane == 0)
                gout[g * 16 + r] = sqrtf(sum / 320.f);
        }
        __syncthreads();   // sbuf reused next iteration
    }

    __threadfence();       // make gout visible device-wide (cross-XCD)
    grid.sync();

    // ---------- Phase B ----------
    if (blockIdx.x < NB) {
        float* gp = gout + (size_t)blockIdx.x * NT;
        for (int t = tid; t < NT; t += TPB) sbuf[t] = gp[t];
        __syncthreads();

        const int LEN   = 20;                  // ceil((NT-1)/256)
        const int start = 1 + tid * LEN;
        const int end   = min(NT, start + LEN);

        float A = 1.f, Bc = 0.f;
        for (int t = start; t < end; ++t) {
            A  *= 0.9f;
            Bc  = 0.9f * Bc + 0.1f * sbuf[t];
        }
        sA[tid] = A; sB[tid] = Bc;
        __syncthreads();

        for (int off = 1; off < TPB; off <<= 1) {
            float a = sA[tid], bb = sB[tid];
            float ap = 1.f, bp = 0.f;
            if (tid >= off) { ap = sA[tid - off]; bp = sB[tid - off]; }
            __syncthreads();
            sA[tid] = a * ap;
            sB[tid] = a * bp + bb;
            __syncthreads();
        }

        float Ap = 1.f, Bp = 0.f;
        if (tid > 0) { Ap = sA[tid - 1]; Bp = sB[tid - 1]; }
        float g = Ap * sbuf[0] + Bp;           // g at t = start-1

        if (tid == 0) gp[0] = sbuf[0];
        for (int t = start; t < end; ++t) {
            g = 0.9f * g + 0.1f * sbuf[t];
            gp[t] = g;
        }
    }

    __threadfence();       // make gains visible device-wide
    grid.sync();

    // ---------- Phase C ----------
    const unsigned n4 = (unsigned)(MAGN / 4);  // 9660000
    const vf4* mag4 = (const vf4*)mag;
    vf4* out4 = (vf4*)out;
    for (unsigned i4 = blockIdx.x * (unsigned)TPB + tid; i4 < n4;
         i4 += gridDim.x * (unsigned)TPB) {
        vf4 m = __builtin_nontemporal_load(&mag4[i4]);
        const unsigned base = i4 * 4u;
        const unsigned row0 = base / NF;          // magic-mul div
        const unsigned row3 = (base + 3u) / NF;   // ≤1 row boundary per 4 elems
        const float ga = __builtin_amdgcn_rcpf(gout[row0] + 0.001f);
        const float gb = __builtin_amdgcn_rcpf(gout[row3] + 0.001f);
        const unsigned lim = (row0 + 1u) * NF;

        vf4 o;
        o.x = m.x * ga;
        o.y = m.y * ((base + 1u < lim) ? ga : gb);
        o.z = m.z * ((base + 2u < lim) ? ga : gb);
        o.w = m.w * gb;
        __builtin_nontemporal_store(o, &out4[i4]);
    }
}

// ---------------- fallback 3-kernel path (proven) ----------------
__global__ __launch_bounds__(256) void x_kernel(const float* __restrict__ mag,
                                                float* __restrict__ gout) {
    __shared__ float sx[16 * NF];
    const int tid  = threadIdx.x;
    const int wave = tid >> 6;
    const int lane = tid & 63;
    const size_t blk_base = (size_t)blockIdx.x * (16 * NF);
    const float4* gp4 = (const float4*)(mag + blk_base);
    float4* sp4 = (float4*)sx;
#pragma unroll
    for (int j = 0; j < 3; ++j) {
        int i4 = tid + 256 * j;
        if (i4 < (16 * NF) / 4) sp4[i4] = gp4[i4];
    }
    __syncthreads();
#pragma unroll
    for (int i = 0; i < 4; ++i) {
        const int r = wave * 4 + i;
        const float* rp = sx + r * NF;
        float sum = 0.f;
#pragma unroll
        for (int k0 = 0; k0 < NF; k0 += 64) {
            int k = k0 + lane;
            if (k < NF) {
                float v = rp[k];
                float w = (k == 0 || k == NF - 1) ? 1.f : 2.f;
                sum += w * v * v;
            }
        }
#pragma unroll
        for (int off = 32; off > 0; off >>= 1)
            sum += __shfl_down(sum, off, 64);
        if (lane == 0)
            gout[blockIdx.x * 16 + r] = sqrtf(sum / 320.f);
    }
}

__global__ __launch_bounds__(256) void scan_kernel(float* __restrict__ gbuf) {
    __shared__ float sx[NT];
    __shared__ float sA[256];
    __shared__ float sB[256];
    const int b   = blockIdx.x;
    const int tid = threadIdx.x;
    float* gp = gbuf + (size_t)b * NT;
    for (int t = tid; t < NT; t += 256) sx[t] = gp[t];
    __syncthreads();
    const int LEN   = 20;
    const int start = 1 + tid * LEN;
    const int end   = min(NT, start + LEN);
    float A = 1.f, Bc = 0.f;
    for (int t = start; t < end; ++t) {
        A  *= 0.9f;
        Bc  = 0.9f * Bc + 0.1f * sx[t];
    }
    sA[tid] = A; sB[tid] = Bc;
    __syncthreads();
    for (int off = 1; off < 256; off <<= 1) {
        float a = sA[tid], bb = sB[tid];
        float ap = 1.f, bp = 0.f;
        if (tid >= off) { ap = sA[tid - off]; bp = sB[tid - off]; }
        __syncthreads();
        sA[tid] = a * ap;
        sB[tid] = a * bp + bb;
        __syncthreads();
    }
    float Ap = 1.f, Bp = 0.f;
    if (tid > 0) { Ap = sA[tid - 1]; Bp = sB[tid - 1]; }
    float g = Ap * sx[0] + Bp;
    if (tid == 0) gp[0] = sx[0];
    for (int t = start; t < end; ++t) {
        g = 0.9f * g + 0.1f * sx[t];
        gp[t] = g;
    }
}

__global__ __launch_bounds__(256) void div_kernel(const float* __restrict__ mag,
                                                  const float* __restrict__ gain,
                                                  float* __restrict__ out) {
    const unsigned n4 = (unsigned)(MAGN / 4);
    const unsigned i4 = blockIdx.x * 256u + threadIdx.x;
    if (i4 >= n4) return;
    const vf4* mag4 = (const vf4*)mag;
    vf4* out4 = (vf4*)out;
    vf4 m = __builtin_nontemporal_load(&mag4[i4]);
    const unsigned base = i4 * 4u;
    const unsigned row0 = base / NF;
    const unsigned row3 = (base + 3u) / NF;
    const float ga = __builtin_amdgcn_rcpf(gain[row0] + 0.001f);
    const float gb = __builtin_amdgcn_rcpf(gain[row3] + 0.001f);
    const unsigned lim = (row0 + 1u) * NF;
    vf4 o;
    o.x = m.x * ga;
    o.y = m.y * ((base + 1u < lim) ? ga : gb);
    o.z = m.z * ((base + 2u < lim) ? ga : gb);
    o.w = m.w * gb;
    __builtin_nontemporal_store(o, &out4[i4]);
}

extern "C" void kernel_launch(void* const* d_in, const int* in_sizes, int n_in,
                              void* d_out, int out_size, void* d_ws, size_t ws_size,
                              hipStream_t stream) {
    const float* mag = (const float*)d_in[0];
    float* out  = (float*)d_out;
    float* gout = out + (size_t)MAGN;          // slice_gain region [B*T]

    void* args[] = {(void*)&mag, (void*)&out, (void*)&gout};
    hipError_t e = hipLaunchCooperativeKernel((const void*)fused_kernel,
                                              dim3(GRID), dim3(TPB),
                                              args, 0, stream);
    if (e != hipSuccess) {
        // fallback: proven 3-kernel pipeline
        x_kernel<<<NROWS / 16, 256, 0, stream>>>(mag, gout);
        scan_kernel<<<NB, 256, 0, stream>>>(gout);
        div_kernel<<<((unsigned)(MAGN / 4) + 255u) / 256u, 256, 0, stream>>>(mag, gout, out);
    }
}

// Round 3
// 292.805 us; speedup vs baseline: 2.1412x; 2.1412x over previous
//
#include <hip/hip_runtime.h>

#define NB 48
#define NT 5000
#define NF 161
#define NROWS (NB * NT)               // 240000
#define MAGN  ((size_t)NROWS * NF)    // 38640000

typedef float vf4 __attribute__((ext_vector_type(4)));

// Kernel A: per-row weighted power + sqrt.
// Block = 256 threads = 16 rows = 2576 floats = 644 float4, staged to LDS via
// global_load_lds dwordx4 (DMA, no VGPR round-trip).  LDS layout is linear
// (wave-uniform base + lane*16 -- exactly the HW pattern), padded to 768
// float4; tail lanes clamp the GLOBAL source only, their LDS writes land in
// the pad.  4 waves then reduce 4 rows each from LDS.
__global__ __launch_bounds__(256) void x_kernel(const float* __restrict__ mag,
                                                float* __restrict__ gout) {
    __shared__ __align__(16) float sx[768 * 4];   // 12288 B (644 data + pad)
    const int tid  = threadIdx.x;
    const int wave = tid >> 6;
    const int lane = tid & 63;
    const size_t blk_base = (size_t)blockIdx.x * (16 * NF);
    const float4* gp4 = (const float4*)(mag + blk_base);
    float4* sp4 = (float4*)sx;

#pragma unroll
    for (int j = 0; j < 3; ++j) {
        const int i4  = tid + 256 * j;
        const int src = (i4 < 644) ? i4 : 643;    // clamp global src; LDS stays linear
        __builtin_amdgcn_global_load_lds(
            (const __attribute__((address_space(1))) void*)(gp4 + src),
            (__attribute__((address_space(3))) void*)(sp4 + i4),
            16, 0, 0);
    }
    __syncthreads();   // drains vmcnt -> LDS staging complete

    // wave w reduces rows w*4 .. w*4+3; lanes read consecutive floats
    // (2 lanes/bank -> conflict-free per m136)
#pragma unroll
    for (int i = 0; i < 4; ++i) {
        const int r = wave * 4 + i;
        const float* rp = sx + r * NF;
        float sum = 0.f;
#pragma unroll
        for (int k0 = 0; k0 < NF; k0 += 64) {
            int k = k0 + lane;
            if (k < NF) {
                float v = rp[k];
                float w = (k == 0 || k == NF - 1) ? 1.f : 2.f;
                sum += w * v * v;
            }
        }
#pragma unroll
        for (int off = 32; off > 0; off >>= 1)
            sum += __shfl_down(sum, off, 64);
        if (lane == 0)
            gout[blockIdx.x * 16 + r] = sqrtf(sum / 320.f);
    }
}

// Kernel B: in-place EMA scan over T per batch.  One block per batch.
// Affine-composite parallel scan: segment == map g -> A*g + B.
__global__ __launch_bounds__(256) void scan_kernel(float* __restrict__ gbuf) {
    __shared__ __align__(16) float sx[NT];        // 20000 B
    __shared__ float sA[256];
    __shared__ float sB[256];
    const int b   = blockIdx.x;
    const int tid = threadIdx.x;
    float* gp = gbuf + (size_t)b * NT;

    // float4 staging load (NT = 5000 = 1250 float4; gbuf 16B-aligned)
    {
        const float4* gp4 = (const float4*)gp;
        float4* sp4 = (float4*)sx;
        for (int i4 = tid; i4 < NT / 4; i4 += 256) sp4[i4] = gp4[i4];
    }
    __syncthreads();

    const int LEN   = 20;                         // ceil((NT-1)/256)
    const int start = 1 + tid * LEN;
    const int end   = min(NT, start + LEN);

    float A = 1.f, Bc = 0.f;
    for (int t = start; t < end; ++t) {
        A  *= 0.9f;
        Bc  = 0.9f * Bc + 0.1f * sx[t];
    }
    sA[tid] = A; sB[tid] = Bc;
    __syncthreads();

    // Hillis-Steele inclusive scan of affine maps
    for (int off = 1; off < 256; off <<= 1) {
        float a = sA[tid], bb = sB[tid];
        float ap = 1.f, bp = 0.f;
        if (tid >= off) { ap = sA[tid - off]; bp = sB[tid - off]; }
        __syncthreads();
        sA[tid] = a * ap;
        sB[tid] = a * bp + bb;
        __syncthreads();
    }

    // exclusive prefix of this thread = inclusive of tid-1; seed g[0] = x[0]
    float Ap = 1.f, Bp = 0.f;
    if (tid > 0) { Ap = sA[tid - 1]; Bp = sB[tid - 1]; }
    float g = Ap * sx[0] + Bp;                    // g at t = start-1

    if (tid == 0) gp[0] = sx[0];
    for (int t = start; t < end; ++t) {
        g = 0.9f * g + 0.1f * sx[t];
        gp[t] = g;
    }
}

// Kernel C: new_mag = mag * rcp(gain[row] + 0.001), float4, grid-stride.
// NT load (mag re-read is dead after use; hits LLC regardless) and NT store
// (out never re-read) keep the LLC holding mag.  2048 blocks x 256 thr =
// 32 waves/CU of TLP; ~18 float4 per thread.
__global__ __launch_bounds__(256) void div_kernel(const float* __restrict__ mag,
                                                  const float* __restrict__ gain,
                                                  float* __restrict__ out) {
    const unsigned n4 = (unsigned)(MAGN / 4);     // 9660000
    const unsigned stride = 2048u * 256u;
    const vf4* mag4 = (const vf4*)mag;
    vf4* out4 = (vf4*)out;

    for (unsigned i4 = blockIdx.x * 256u + threadIdx.x; i4 < n4; i4 += stride) {
        vf4 m = __builtin_nontemporal_load(&mag4[i4]);
        const unsigned base = i4 * 4u;
        const unsigned row0 = base / NF;          // magic-mul div by 161
        const unsigned row3 = (base + 3u) / NF;   // at most one row boundary in 4 elems
        const float ga = __builtin_amdgcn_rcpf(gain[row0] + 0.001f);
        const float gb = __builtin_amdgcn_rcpf(gain[row3] + 0.001f);
        const unsigned lim = (row0 + 1u) * NF;    // first index of next row

        vf4 o;
        o.x = m.x * ga;
        o.y = m.y * ((base + 1u < lim) ? ga : gb);
        o.z = m.z * ((base + 2u < lim) ? ga : gb);
        o.w = m.w * gb;
        __builtin_nontemporal_store(o, &out4[i4]);
    }
}

extern "C" void kernel_launch(void* const* d_in, const int* in_sizes, int n_in,
                              void* d_out, int out_size, void* d_ws, size_t ws_size,
                              hipStream_t stream) {
    const float* mag = (const float*)d_in[0];
    float* out  = (float*)d_out;
    float* gout = out + (size_t)MAGN;             // slice_gain region [B*T]

    x_kernel<<<NROWS / 16, 256, 0, stream>>>(mag, gout);
    scan_kernel<<<NB, 256, 0, stream>>>(gout);
    div_kernel<<<2048, 256, 0, stream>>>(mag, gout, out);
}